// Round 1
// baseline (378.185 us; speedup 1.0000x reference)
//
#include <hip/hip_runtime.h>
#include <math.h>

#define BATCH   16
#define SPATIAL 16384   // 128*128
#define NCHAN   256
#define KK      8

// ---------- sorted-list update helpers (branch-free, fully unrolled) ----------
// t[0..7] sorted descending (t[0] = max). Keep top-8 after seeing v.
__device__ __forceinline__ void upd_top(float (&t)[8], float v) {
  t[7] = fmaxf(t[7], v);           // discard min(old t7, v)
  #pragma unroll
  for (int j = 7; j >= 1; --j) {   // one bubble pass restores sortedness
    float hi = fmaxf(t[j - 1], t[j]);
    float lo = fminf(t[j - 1], t[j]);
    t[j - 1] = hi;
    t[j]     = lo;
  }
}

// b[0..7] sorted ascending (b[0] = min). Keep bottom-8 after seeing v.
__device__ __forceinline__ void upd_bot(float (&bo)[8], float v) {
  bo[7] = fminf(bo[7], v);
  #pragma unroll
  for (int j = 7; j >= 1; --j) {
    float lo = fminf(bo[j - 1], bo[j]);
    float hi = fmaxf(bo[j - 1], bo[j]);
    bo[j - 1] = lo;
    bo[j]     = hi;
  }
}

// ---------- kernel 1: per-(chunk, channel) partial top-8 / bottom-8 ----------
// grid = (NC, BATCH), block = 256. Thread layout: g = tid>>6 (position group),
// lane = tid&63 owns channels 4*lane..4*lane+3 via float4 (perfect coalescing:
// one wave-load = 1 KiB contiguous).
// Record layout in ws: part[((b*NC + chunk)*NCHAN + c)*16 + k], k<8 top desc,
// k in 8..15 bottom asc.
__global__ __launch_bounds__(256, 4) void topk_partial(
    const float* __restrict__ in, float* __restrict__ part, int NC) {
  const int chunk = blockIdx.x;
  const int b     = blockIdx.y;
  const int tid   = threadIdx.x;
  const int g     = tid >> 6;
  const int lane  = tid & 63;
  const int cb    = lane << 2;           // channel base for this thread
  const int CHUNK = SPATIAL / NC;        // positions per block
  const int iters = CHUNK >> 2;          // positions per thread (per g-group)

  float t[4][8], bo[4][8];
  #pragma unroll
  for (int ch = 0; ch < 4; ++ch) {
    #pragma unroll
    for (int k = 0; k < 8; ++k) {
      t[ch][k]  = -INFINITY;
      bo[ch][k] =  INFINITY;
    }
  }

  // positions: chunk*CHUNK + g + 4*i  (i = 0..iters-1), wave-uniform position
  const float* base =
      in + ((size_t)b * SPATIAL + (size_t)chunk * CHUNK + g) * NCHAN + cb;

  #pragma unroll 4
  for (int i = 0; i < iters; ++i) {
    float4 v = *reinterpret_cast<const float4*>(base + (size_t)i * 4 * NCHAN);
    upd_top(t[0], v.x);  upd_bot(bo[0], v.x);
    upd_top(t[1], v.y);  upd_bot(bo[1], v.y);
    upd_top(t[2], v.z);  upd_bot(bo[2], v.z);
    upd_top(t[3], v.w);  upd_bot(bo[3], v.w);
  }

  // ---- block epilogue: merge the 4 position-groups per channel via LDS ----
  __shared__ float sm[4][NCHAN][9];   // pad 8->9 to spread banks; 36 KiB

  // pass 1: tops
  #pragma unroll
  for (int ch = 0; ch < 4; ++ch) {
    #pragma unroll
    for (int k = 0; k < 8; ++k) sm[g][cb + ch][k] = t[ch][k];
  }
  __syncthreads();
  {
    const int c = tid;                 // one channel per thread
    float m[8];
    #pragma unroll
    for (int k = 0; k < 8; ++k) m[k] = sm[0][c][k];
    #pragma unroll
    for (int g2 = 1; g2 < 4; ++g2) {
      #pragma unroll
      for (int k = 0; k < 8; ++k) upd_top(m, sm[g2][c][k]);
    }
    float* rec = part + ((size_t)(b * NC + chunk) * NCHAN + c) * 16;
    #pragma unroll
    for (int k = 0; k < 8; ++k) rec[k] = m[k];
  }
  __syncthreads();

  // pass 2: bottoms (reuse sm)
  #pragma unroll
  for (int ch = 0; ch < 4; ++ch) {
    #pragma unroll
    for (int k = 0; k < 8; ++k) sm[g][cb + ch][k] = bo[ch][k];
  }
  __syncthreads();
  {
    const int c = tid;
    float m[8];
    #pragma unroll
    for (int k = 0; k < 8; ++k) m[k] = sm[0][c][k];
    #pragma unroll
    for (int g2 = 1; g2 < 4; ++g2) {
      #pragma unroll
      for (int k = 0; k < 8; ++k) upd_bot(m, sm[g2][c][k]);
    }
    float* rec = part + ((size_t)(b * NC + chunk) * NCHAN + c) * 16;
    #pragma unroll
    for (int k = 0; k < 8; ++k) rec[8 + k] = m[k];
  }
}

// ---------- kernel 2: one wave per (b,c), merge NC partial lists ----------
// Lane l holds chunk l's sorted lists; 8x wave-max (then wave-min) extraction.
__global__ __launch_bounds__(256) void topk_merge(
    const float* __restrict__ part, float* __restrict__ out, int NC) {
  const int tid  = threadIdx.x;
  const int lane = tid & 63;
  const int w    = tid >> 6;
  const int wid  = blockIdx.x * 4 + w;   // 0..BATCH*NCHAN-1
  const int b    = wid >> 8;             // NCHAN == 256
  const int c    = wid & 255;

  float t[8], bo[8];
  if (lane < NC) {
    const float* rec = part + ((size_t)(b * NC + lane) * NCHAN + c) * 16;
    float4 a0 = *reinterpret_cast<const float4*>(rec);
    float4 a1 = *reinterpret_cast<const float4*>(rec + 4);
    float4 b0 = *reinterpret_cast<const float4*>(rec + 8);
    float4 b1 = *reinterpret_cast<const float4*>(rec + 12);
    t[0] = a0.x; t[1] = a0.y; t[2] = a0.z; t[3] = a0.w;
    t[4] = a1.x; t[5] = a1.y; t[6] = a1.z; t[7] = a1.w;
    bo[0] = b0.x; bo[1] = b0.y; bo[2] = b0.z; bo[3] = b0.w;
    bo[4] = b1.x; bo[5] = b1.y; bo[6] = b1.z; bo[7] = b1.w;
  } else {
    #pragma unroll
    for (int k = 0; k < 8; ++k) { t[k] = -INFINITY; bo[k] = INFINITY; }
  }

  float* o = out + ((size_t)b * NCHAN + c) * 16;

  // ---- top-8, descending ----
  {
    float cand = t[0];
    #pragma unroll
    for (int k = 0; k < KK; ++k) {
      float m = cand;
      #pragma unroll
      for (int off = 32; off >= 1; off >>= 1) m = fmaxf(m, __shfl_xor(m, off));
      if (lane == 0) o[k] = m;
      unsigned long long ball = __ballot(cand == m);
      int first = __ffsll(ball) - 1;     // exactly one lane advances (tie-safe)
      if (lane == first) {
        #pragma unroll
        for (int j = 0; j < 7; ++j) t[j] = t[j + 1];
        t[7] = -INFINITY;
        cand = t[0];
      }
    }
  }

  // ---- bottom-8, ascending ----
  {
    float cand = bo[0];
    #pragma unroll
    for (int k = 0; k < KK; ++k) {
      float m = cand;
      #pragma unroll
      for (int off = 32; off >= 1; off >>= 1) m = fminf(m, __shfl_xor(m, off));
      if (lane == 0) o[8 + k] = m;
      unsigned long long ball = __ballot(cand == m);
      int first = __ffsll(ball) - 1;
      if (lane == first) {
        #pragma unroll
        for (int j = 0; j < 7; ++j) bo[j] = bo[j + 1];
        bo[7] = INFINITY;
        cand = bo[0];
      }
    }
  }
}

extern "C" void kernel_launch(void* const* d_in, const int* in_sizes, int n_in,
                              void* d_out, int out_size, void* d_ws, size_t ws_size,
                              hipStream_t stream) {
  const float* in  = (const float*)d_in[0];
  float*       out = (float*)d_out;
  float*       part = (float*)d_ws;

  // NC chunks per batch; workspace = BATCH*NC*NCHAN*16 floats (16 MiB at NC=64).
  int NC = 64;
  while ((size_t)BATCH * NC * NCHAN * 16 * sizeof(float) > ws_size && NC > 4)
    NC >>= 1;

  dim3 g1(NC, BATCH);
  topk_partial<<<g1, 256, 0, stream>>>(in, part, NC);

  const int nwaves = BATCH * NCHAN;           // 4096
  topk_merge<<<nwaves / 4, 256, 0, stream>>>(part, out, NC);
}

// Round 2
// 366.895 us; speedup vs baseline: 1.0308x; 1.0308x over previous
//
#include <hip/hip_runtime.h>
#include <math.h>

#define BATCH   16
#define SPATIAL 16384   // 128*128
#define NCHAN   256
#define KK      8

// ---------------- compare-exchange primitives ----------------
#define CE_DESC(a, b) { float _hi = fmaxf(a, b), _lo = fminf(a, b); a = _hi; b = _lo; }
#define CE_ASC(a, b)  { float _lo = fminf(a, b), _hi = fmaxf(a, b); a = _lo; b = _hi; }

// Batcher odd-even mergesort, 8 elems, 19 CE, descending (v[0] = max).
__device__ __forceinline__ void sort8_desc(float (&v)[8]) {
  CE_DESC(v[0], v[1]); CE_DESC(v[2], v[3]); CE_DESC(v[4], v[5]); CE_DESC(v[6], v[7]);
  CE_DESC(v[0], v[2]); CE_DESC(v[1], v[3]); CE_DESC(v[4], v[6]); CE_DESC(v[5], v[7]);
  CE_DESC(v[1], v[2]); CE_DESC(v[5], v[6]);
  CE_DESC(v[0], v[4]); CE_DESC(v[1], v[5]); CE_DESC(v[2], v[6]); CE_DESC(v[3], v[7]);
  CE_DESC(v[2], v[4]); CE_DESC(v[3], v[5]);
  CE_DESC(v[1], v[2]); CE_DESC(v[3], v[4]); CE_DESC(v[5], v[6]);
}

// Bitonic -> sorted descending (12 CE). Input must be bitonic.
__device__ __forceinline__ void bimerge8_desc(float (&t)[8]) {
  CE_DESC(t[0], t[4]); CE_DESC(t[1], t[5]); CE_DESC(t[2], t[6]); CE_DESC(t[3], t[7]);
  CE_DESC(t[0], t[2]); CE_DESC(t[1], t[3]); CE_DESC(t[4], t[6]); CE_DESC(t[5], t[7]);
  CE_DESC(t[0], t[1]); CE_DESC(t[2], t[3]); CE_DESC(t[4], t[5]); CE_DESC(t[6], t[7]);
}

// Bitonic -> sorted ascending (12 CE).
__device__ __forceinline__ void bimerge8_asc(float (&t)[8]) {
  CE_ASC(t[0], t[4]); CE_ASC(t[1], t[5]); CE_ASC(t[2], t[6]); CE_ASC(t[3], t[7]);
  CE_ASC(t[0], t[2]); CE_ASC(t[1], t[3]); CE_ASC(t[4], t[6]); CE_ASC(t[5], t[7]);
  CE_ASC(t[0], t[1]); CE_ASC(t[2], t[3]); CE_ASC(t[4], t[5]); CE_ASC(t[6], t[7]);
}

// t sorted desc, s sorted desc -> t = top-8 of union, sorted desc.
// Half-cleaner (multiset of top-8 = elementwise max(t[j], s[7-j])) + bitonic merge.
__device__ __forceinline__ void merge_top(float (&t)[8], const float (&s)[8]) {
  #pragma unroll
  for (int j = 0; j < 8; ++j) t[j] = fmaxf(t[j], s[7 - j]);
  bimerge8_desc(t);
}

// bo sorted asc, s sorted DESC -> bo = bottom-8 of union, sorted asc.
__device__ __forceinline__ void merge_bot_from_desc(float (&bo)[8], const float (&s)[8]) {
  #pragma unroll
  for (int j = 0; j < 8; ++j) bo[j] = fminf(bo[j], s[j]);
  bimerge8_asc(bo);
}

// A asc, B asc -> A = bottom-8 of union, sorted asc.
__device__ __forceinline__ void merge_bot_asc(float (&a)[8], const float (&b)[8]) {
  #pragma unroll
  for (int j = 0; j < 8; ++j) a[j] = fminf(a[j], b[7 - j]);
  bimerge8_asc(a);
}

// ---------- kernel 1: per-(chunk, channel) partial top-8 / bottom-8 ----------
// grid = (NC, BATCH), block = 256. Thread owns 2 channels (float2 loads:
// 64 lanes x 8 B = 512 B contiguous per wave-load). g = tid>>7 in {0,1} is the
// position group; positions g + 2*i. Batch-8 bitonic update: 12.75 ops/elem.
__global__ __launch_bounds__(256, 4) void topk_partial(
    const float* __restrict__ in, float* __restrict__ part, int NC) {
  const int chunk = blockIdx.x;
  const int b     = blockIdx.y;
  const int tid   = threadIdx.x;
  const int g     = tid >> 7;            // 0..1
  const int cp    = tid & 127;           // channel-pair index
  const int cb    = cp << 1;             // channel base
  const int CHUNK = SPATIAL / NC;        // 256 positions per block
  const int ppt   = CHUNK >> 1;          // 128 positions per thread
  const int MB    = ppt >> 3;            // 16 macro-iters of 8 positions

  float t0[8], t1[8], b0_[8], b1_[8];
  #pragma unroll
  for (int k = 0; k < 8; ++k) {
    t0[k] = -INFINITY; t1[k] = -INFINITY;
    b0_[k] = INFINITY; b1_[k] = INFINITY;
  }

  const float* base =
      in + ((size_t)b * SPATIAL + (size_t)chunk * CHUNK + g) * NCHAN + cb;

  for (int mi = 0; mi < MB; ++mi) {
    float2 v[8];
    #pragma unroll
    for (int j = 0; j < 8; ++j)
      v[j] = *reinterpret_cast<const float2*>(
          base + (size_t)(mi * 8 + j) * 2 * NCHAN);

    float s0[8], s1[8];
    #pragma unroll
    for (int j = 0; j < 8; ++j) { s0[j] = v[j].x; s1[j] = v[j].y; }

    sort8_desc(s0);
    merge_top(t0, s0);
    merge_bot_from_desc(b0_, s0);

    sort8_desc(s1);
    merge_top(t1, s1);
    merge_bot_from_desc(b1_, s1);
  }

  // ---- block epilogue: merge the 2 position-groups per channel via LDS ----
  __shared__ float sm[2][NCHAN][9];   // pad 8->9; 18 KiB

  // pass 1: tops
  #pragma unroll
  for (int k = 0; k < 8; ++k) { sm[g][cb][k] = t0[k]; sm[g][cb + 1][k] = t1[k]; }
  __syncthreads();
  {
    const int c = tid;                 // one channel per thread
    float m[8], s[8];
    #pragma unroll
    for (int k = 0; k < 8; ++k) { m[k] = sm[0][c][k]; s[k] = sm[1][c][k]; }
    merge_top(m, s);
    float* rec = part + ((size_t)(b * NC + chunk) * NCHAN + c) * 16;
    #pragma unroll
    for (int k = 0; k < 8; ++k) rec[k] = m[k];
  }
  __syncthreads();

  // pass 2: bottoms
  #pragma unroll
  for (int k = 0; k < 8; ++k) { sm[g][cb][k] = b0_[k]; sm[g][cb + 1][k] = b1_[k]; }
  __syncthreads();
  {
    const int c = tid;
    float m[8], s[8];
    #pragma unroll
    for (int k = 0; k < 8; ++k) { m[k] = sm[0][c][k]; s[k] = sm[1][c][k]; }
    merge_bot_asc(m, s);
    float* rec = part + ((size_t)(b * NC + chunk) * NCHAN + c) * 16;
    #pragma unroll
    for (int k = 0; k < 8; ++k) rec[8 + k] = m[k];
  }
}

// ---------- kernel 2: one wave per (b,c), merge NC partial lists ----------
__global__ __launch_bounds__(256) void topk_merge(
    const float* __restrict__ part, float* __restrict__ out, int NC) {
  const int tid  = threadIdx.x;
  const int lane = tid & 63;
  const int w    = tid >> 6;
  const int wid  = blockIdx.x * 4 + w;   // 0..BATCH*NCHAN-1
  const int b    = wid >> 8;             // NCHAN == 256
  const int c    = wid & 255;

  float t[8], bo[8];
  if (lane < NC) {
    const float* rec = part + ((size_t)(b * NC + lane) * NCHAN + c) * 16;
    float4 a0 = *reinterpret_cast<const float4*>(rec);
    float4 a1 = *reinterpret_cast<const float4*>(rec + 4);
    float4 c0 = *reinterpret_cast<const float4*>(rec + 8);
    float4 c1 = *reinterpret_cast<const float4*>(rec + 12);
    t[0] = a0.x; t[1] = a0.y; t[2] = a0.z; t[3] = a0.w;
    t[4] = a1.x; t[5] = a1.y; t[6] = a1.z; t[7] = a1.w;
    bo[0] = c0.x; bo[1] = c0.y; bo[2] = c0.z; bo[3] = c0.w;
    bo[4] = c1.x; bo[5] = c1.y; bo[6] = c1.z; bo[7] = c1.w;
  } else {
    #pragma unroll
    for (int k = 0; k < 8; ++k) { t[k] = -INFINITY; bo[k] = INFINITY; }
  }

  float* o = out + ((size_t)b * NCHAN + c) * 16;

  // ---- top-8, descending ----
  {
    float cand = t[0];
    #pragma unroll
    for (int k = 0; k < KK; ++k) {
      float m = cand;
      #pragma unroll
      for (int off = 32; off >= 1; off >>= 1) m = fmaxf(m, __shfl_xor(m, off));
      if (lane == 0) o[k] = m;
      unsigned long long ball = __ballot(cand == m);
      int first = __ffsll(ball) - 1;     // exactly one lane advances (tie-safe)
      if (lane == first) {
        #pragma unroll
        for (int j = 0; j < 7; ++j) t[j] = t[j + 1];
        t[7] = -INFINITY;
        cand = t[0];
      }
    }
  }

  // ---- bottom-8, ascending ----
  {
    float cand = bo[0];
    #pragma unroll
    for (int k = 0; k < KK; ++k) {
      float m = cand;
      #pragma unroll
      for (int off = 32; off >= 1; off >>= 1) m = fminf(m, __shfl_xor(m, off));
      if (lane == 0) o[8 + k] = m;
      unsigned long long ball = __ballot(cand == m);
      int first = __ffsll(ball) - 1;
      if (lane == first) {
        #pragma unroll
        for (int j = 0; j < 7; ++j) bo[j] = bo[j + 1];
        bo[7] = INFINITY;
        cand = bo[0];
      }
    }
  }
}

extern "C" void kernel_launch(void* const* d_in, const int* in_sizes, int n_in,
                              void* d_out, int out_size, void* d_ws, size_t ws_size,
                              hipStream_t stream) {
  const float* in   = (const float*)d_in[0];
  float*       out  = (float*)d_out;
  float*       part = (float*)d_ws;

  // NC chunks per batch; workspace = BATCH*NC*NCHAN*16 floats (16 MiB at NC=64).
  int NC = 64;
  while ((size_t)BATCH * NC * NCHAN * 16 * sizeof(float) > ws_size && NC > 4)
    NC >>= 1;

  dim3 g1(NC, BATCH);
  topk_partial<<<g1, 256, 0, stream>>>(in, part, NC);

  const int nwaves = BATCH * NCHAN;           // 4096
  topk_merge<<<nwaves / 4, 256, 0, stream>>>(part, out, NC);
}